// Round 1
// baseline (1635.210 us; speedup 1.0000x reference)
//
#include <hip/hip_runtime.h>
#include <math.h>

// Problem constants (from reference)
#define L_SEQ 131072
#define NSTATE 256
#define HDIM   256
#define LC     128                 // chunk length for blocked scan
#define NCHUNK (L_SEQ / LC)        // 1024 chunks

// GEMM tiling
#define BM 64
#define BN 64
#define BK 16

// ---------------------------------------------------------------------------
// K0: prep — Lambda, Lambda^LC, B_norm = (B_re + i B_im) * exp(gamma_log)
// grid: (NSTATE) blocks x (HDIM) threads
// ---------------------------------------------------------------------------
__global__ void prep_kernel(const float* __restrict__ nu_log,
                            const float* __restrict__ theta_log,
                            const float* __restrict__ B_re,
                            const float* __restrict__ B_im,
                            const float* __restrict__ gamma_log,
                            float* __restrict__ Bre_n,
                            float* __restrict__ Bim_n,
                            float2* __restrict__ Lambda,
                            float2* __restrict__ lamLc) {
    int n = blockIdx.x;
    int h = threadIdx.x;
    float g = expf(gamma_log[n]);
    Bre_n[n * HDIM + h] = B_re[n * HDIM + h] * g;
    Bim_n[n * HDIM + h] = B_im[n * HDIM + h] * g;
    if (h == 0) {
        float a = expf(nu_log[n]);      // decay rate
        float b = expf(theta_log[n]);   // phase
        float r = expf(-a);
        Lambda[n] = make_float2(r * cosf(b), r * sinf(b));
        float rl = expf(-a * (float)LC);
        float bl = b * (float)LC;
        lamLc[n] = make_float2(rl * cosf(bl), rl * sinf(bl));
    }
}

// ---------------------------------------------------------------------------
// K1: GEMM1 — Bu[l][n] = sum_h x[l][h] * Bnorm[n][h]   (re & im)
// fp32 VALU, 64x64 tile, BK=16, 256 threads, 4x4 micro-tile per thread
// grid: (NSTATE/BN, L_SEQ/BM)  — n-tiles fastest for x L2 reuse
// ---------------------------------------------------------------------------
__launch_bounds__(256)
__global__ void gemm1_kernel(const float* __restrict__ x,
                             const float* __restrict__ Bre,
                             const float* __restrict__ Bim,
                             float2* __restrict__ Bu) {
    __shared__ float sX[BK][BM + 1];
    __shared__ float sBr[BK][BN + 1];
    __shared__ float sBi[BK][BN + 1];

    const int n0 = blockIdx.x * BN;
    const int l0 = blockIdx.y * BM;
    const int tid = threadIdx.x;
    const int tr = tid >> 4;        // 0..15 -> output row group
    const int tc = tid & 15;        // 0..15 -> output col group
    const int lr = tid >> 2;        // 0..63 load row
    const int kq = (tid & 3) << 2;  // 0,4,8,12 load k offset

    float accR[4][4] = {};
    float accI[4][4] = {};

    for (int kt = 0; kt < HDIM; kt += BK) {
        float4 vx = *(const float4*)&x[(size_t)(l0 + lr) * HDIM + kt + kq];
        float4 vr = *(const float4*)&Bre[(size_t)(n0 + lr) * HDIM + kt + kq];
        float4 vi = *(const float4*)&Bim[(size_t)(n0 + lr) * HDIM + kt + kq];
        __syncthreads();
        sX[kq + 0][lr] = vx.x; sX[kq + 1][lr] = vx.y;
        sX[kq + 2][lr] = vx.z; sX[kq + 3][lr] = vx.w;
        sBr[kq + 0][lr] = vr.x; sBr[kq + 1][lr] = vr.y;
        sBr[kq + 2][lr] = vr.z; sBr[kq + 3][lr] = vr.w;
        sBi[kq + 0][lr] = vi.x; sBi[kq + 1][lr] = vi.y;
        sBi[kq + 2][lr] = vi.z; sBi[kq + 3][lr] = vi.w;
        __syncthreads();
        #pragma unroll
        for (int k = 0; k < BK; ++k) {
            float a[4], br[4], bi[4];
            #pragma unroll
            for (int i = 0; i < 4; ++i) a[i] = sX[k][tr * 4 + i];
            #pragma unroll
            for (int j = 0; j < 4; ++j) { br[j] = sBr[k][tc * 4 + j]; bi[j] = sBi[k][tc * 4 + j]; }
            #pragma unroll
            for (int i = 0; i < 4; ++i)
                #pragma unroll
                for (int j = 0; j < 4; ++j) {
                    accR[i][j] = fmaf(a[i], br[j], accR[i][j]);
                    accI[i][j] = fmaf(a[i], bi[j], accI[i][j]);
                }
        }
    }
    #pragma unroll
    for (int i = 0; i < 4; ++i) {
        int l = l0 + tr * 4 + i;
        #pragma unroll
        for (int j = 0; j < 4; ++j) {
            int n = n0 + tc * 4 + j;
            Bu[(size_t)l * NSTATE + n] = make_float2(accR[i][j], accI[i][j]);
        }
    }
}

// ---------------------------------------------------------------------------
// K2: scan phase 1 — per-chunk local scan (from zero), write chunk-final state
// grid: NCHUNK blocks x NSTATE threads (thread n = channel n)
// ---------------------------------------------------------------------------
__launch_bounds__(256)
__global__ void scan1_kernel(const float2* __restrict__ Bu,
                             const float2* __restrict__ Lambda,
                             float2* __restrict__ chunk_local) {
    const int c = blockIdx.x;
    const int n = threadIdx.x;
    const float2 lam = Lambda[n];
    float zr = 0.f, zi = 0.f;
    const float2* p = Bu + (size_t)c * LC * NSTATE + n;
    #pragma unroll 8
    for (int l = 0; l < LC; ++l) {
        float2 bu = p[(size_t)l * NSTATE];
        float nzr = fmaf(lam.x, zr, fmaf(-lam.y, zi, bu.x));
        float nzi = fmaf(lam.x, zi, fmaf(lam.y, zr, bu.y));
        zr = nzr; zi = nzi;
    }
    chunk_local[c * NSTATE + n] = make_float2(zr, zi);
}

// ---------------------------------------------------------------------------
// K3: scan phase 2 — sequential scan over chunk carries
// grid: 1 block x NSTATE threads; carry[c] = lamLc*carry[c-1] + local[c]
// chunk_prefix[c] = exact state at the END of chunk c
// ---------------------------------------------------------------------------
__launch_bounds__(256)
__global__ void scan2_kernel(const float2* __restrict__ chunk_local,
                             const float2* __restrict__ lamLc,
                             float2* __restrict__ chunk_prefix) {
    const int n = threadIdx.x;
    const float2 lam = lamLc[n];
    float zr = 0.f, zi = 0.f;
    #pragma unroll 4
    for (int c = 0; c < NCHUNK; ++c) {
        float2 b = chunk_local[c * NSTATE + n];
        float nzr = fmaf(lam.x, zr, fmaf(-lam.y, zi, b.x));
        float nzi = fmaf(lam.x, zi, fmaf(lam.y, zr, b.y));
        zr = nzr; zi = nzi;
        chunk_prefix[c * NSTATE + n] = make_float2(zr, zi);
    }
}

// ---------------------------------------------------------------------------
// K4: scan phase 3 — re-scan chunk with true carry-in, write states in-place
// grid: NCHUNK blocks x NSTATE threads
// ---------------------------------------------------------------------------
__launch_bounds__(256)
__global__ void scan3_kernel(float2* __restrict__ Bu,
                             const float2* __restrict__ Lambda,
                             const float2* __restrict__ chunk_prefix) {
    const int c = blockIdx.x;
    const int n = threadIdx.x;
    const float2 lam = Lambda[n];
    float zr = 0.f, zi = 0.f;
    if (c > 0) {
        float2 z0 = chunk_prefix[(c - 1) * NSTATE + n];
        zr = z0.x; zi = z0.y;
    }
    float2* p = Bu + (size_t)c * LC * NSTATE + n;
    #pragma unroll 8
    for (int l = 0; l < LC; ++l) {
        float2 bu = p[(size_t)l * NSTATE];
        float nzr = fmaf(lam.x, zr, fmaf(-lam.y, zi, bu.x));
        float nzi = fmaf(lam.x, zi, fmaf(lam.y, zr, bu.y));
        zr = nzr; zi = nzi;
        p[(size_t)l * NSTATE] = make_float2(zr, zi);
    }
}

// ---------------------------------------------------------------------------
// K5: GEMM2 — y[l][h] = sum_n (Cre[h][n]*zr[l][n] - Cim[h][n]*zi[l][n]) + D[h]*x[l][h]
// grid: (HDIM/BN, L_SEQ/BM) — h-tiles fastest for Z L2 reuse
// ---------------------------------------------------------------------------
__launch_bounds__(256)
__global__ void gemm2_kernel(const float2* __restrict__ Z,
                             const float* __restrict__ Cre,
                             const float* __restrict__ Cim,
                             const float* __restrict__ Dvec,
                             const float* __restrict__ x,
                             float* __restrict__ out) {
    __shared__ float sZr[BK][BM + 1];
    __shared__ float sZi[BK][BM + 1];
    __shared__ float sCr[BK][BN + 1];
    __shared__ float sCi[BK][BN + 1];

    const int h0 = blockIdx.x * BN;
    const int l0 = blockIdx.y * BM;
    const int tid = threadIdx.x;
    const int tr = tid >> 4;
    const int tc = tid & 15;
    const int lr = tid >> 2;          // C load row (0..63)
    const int kq = (tid & 3) << 2;    // C load k offset
    const int zrow = tid >> 3;        // Z load row (0..31)
    const int znp = (tid & 7) << 1;   // Z load n-pair base (0,2,..,14)

    float acc[4][4] = {};

    for (int kt = 0; kt < NSTATE; kt += BK) {
        float4 vc = *(const float4*)&Cre[(size_t)(h0 + lr) * NSTATE + kt + kq];
        float4 vi = *(const float4*)&Cim[(size_t)(h0 + lr) * NSTATE + kt + kq];
        float4 vz0 = *(const float4*)&Z[(size_t)(l0 + zrow) * NSTATE + kt + znp];
        float4 vz1 = *(const float4*)&Z[(size_t)(l0 + zrow + 32) * NSTATE + kt + znp];
        __syncthreads();
        sCr[kq + 0][lr] = vc.x; sCr[kq + 1][lr] = vc.y;
        sCr[kq + 2][lr] = vc.z; sCr[kq + 3][lr] = vc.w;
        sCi[kq + 0][lr] = vi.x; sCi[kq + 1][lr] = vi.y;
        sCi[kq + 2][lr] = vi.z; sCi[kq + 3][lr] = vi.w;
        sZr[znp + 0][zrow] = vz0.x; sZi[znp + 0][zrow] = vz0.y;
        sZr[znp + 1][zrow] = vz0.z; sZi[znp + 1][zrow] = vz0.w;
        sZr[znp + 0][zrow + 32] = vz1.x; sZi[znp + 0][zrow + 32] = vz1.y;
        sZr[znp + 1][zrow + 32] = vz1.z; sZi[znp + 1][zrow + 32] = vz1.w;
        __syncthreads();
        #pragma unroll
        for (int k = 0; k < BK; ++k) {
            float zr4[4], zi4[4], cr[4], ci[4];
            #pragma unroll
            for (int i = 0; i < 4; ++i) { zr4[i] = sZr[k][tr * 4 + i]; zi4[i] = sZi[k][tr * 4 + i]; }
            #pragma unroll
            for (int j = 0; j < 4; ++j) { cr[j] = sCr[k][tc * 4 + j]; ci[j] = sCi[k][tc * 4 + j]; }
            #pragma unroll
            for (int i = 0; i < 4; ++i)
                #pragma unroll
                for (int j = 0; j < 4; ++j) {
                    acc[i][j] = fmaf(zr4[i], cr[j], acc[i][j]);
                    acc[i][j] = fmaf(-zi4[i], ci[j], acc[i][j]);
                }
        }
    }
    #pragma unroll
    for (int i = 0; i < 4; ++i) {
        int l = l0 + tr * 4 + i;
        #pragma unroll
        for (int j = 0; j < 4; ++j) {
            int h = h0 + tc * 4 + j;
            float xv = x[(size_t)l * HDIM + h];
            out[(size_t)l * HDIM + h] = fmaf(Dvec[h], xv, acc[i][j]);
        }
    }
}

// ---------------------------------------------------------------------------
// Host launch
// ---------------------------------------------------------------------------
extern "C" void kernel_launch(void* const* d_in, const int* in_sizes, int n_in,
                              void* d_out, int out_size, void* d_ws, size_t ws_size,
                              hipStream_t stream) {
    const float* x         = (const float*)d_in[0];
    const float* nu_log    = (const float*)d_in[1];
    const float* theta_log = (const float*)d_in[2];
    const float* B_re      = (const float*)d_in[3];
    const float* B_im      = (const float*)d_in[4];
    const float* C_re      = (const float*)d_in[5];
    const float* C_im      = (const float*)d_in[6];
    const float* Dvec      = (const float*)d_in[7];
    const float* gamma_log = (const float*)d_in[8];
    float* out = (float*)d_out;

    // Workspace layout (bytes)
    char* ws = (char*)d_ws;
    const size_t BU_BYTES     = (size_t)L_SEQ * NSTATE * sizeof(float2);   // 268 MB (Bu, then states in-place)
    const size_t BN_BYTES     = (size_t)NSTATE * HDIM * sizeof(float);     // 256 KB each
    const size_t LAM_BYTES    = (size_t)NSTATE * sizeof(float2);
    const size_t CHUNK_BYTES  = (size_t)NCHUNK * NSTATE * sizeof(float2);  // 2 MB each

    size_t off = 0;
    float2* Bu          = (float2*)(ws + off); off += BU_BYTES;
    float*  Bre_n       = (float*)(ws + off);  off += BN_BYTES;
    float*  Bim_n       = (float*)(ws + off);  off += BN_BYTES;
    float2* Lambda      = (float2*)(ws + off); off += LAM_BYTES;
    float2* lamLc       = (float2*)(ws + off); off += LAM_BYTES;
    float2* chunk_local = (float2*)(ws + off); off += CHUNK_BYTES;
    float2* chunk_pref  = (float2*)(ws + off); off += CHUNK_BYTES;

    if (ws_size < off) return;  // insufficient scratch: fail validation cleanly

    prep_kernel<<<dim3(NSTATE), dim3(HDIM), 0, stream>>>(
        nu_log, theta_log, B_re, B_im, gamma_log, Bre_n, Bim_n, Lambda, lamLc);

    gemm1_kernel<<<dim3(NSTATE / BN, L_SEQ / BM), dim3(256), 0, stream>>>(
        x, Bre_n, Bim_n, Bu);

    scan1_kernel<<<dim3(NCHUNK), dim3(NSTATE), 0, stream>>>(Bu, Lambda, chunk_local);
    scan2_kernel<<<dim3(1), dim3(NSTATE), 0, stream>>>(chunk_local, lamLc, chunk_pref);
    scan3_kernel<<<dim3(NCHUNK), dim3(NSTATE), 0, stream>>>(Bu, Lambda, chunk_pref);

    gemm2_kernel<<<dim3(HDIM / BN, L_SEQ / BM), dim3(256), 0, stream>>>(
        Bu, C_re, C_im, Dvec, x, out);
}

// Round 2
// 587.939 us; speedup vs baseline: 2.7813x; 2.7813x over previous
//
#include <hip/hip_runtime.h>
#include <math.h>

// Problem constants
#define L_SEQ 131072
#define NSTATE 256
#define HDIM   256
#define KDIM   512            // 2*NSTATE: re/im interleaved columns
#define LC     128            // scan chunk length
#define NCHUNK (L_SEQ / LC)   // 1024

typedef __bf16 bf16x8 __attribute__((ext_vector_type(8)));
typedef float  f32x4  __attribute__((ext_vector_type(4)));

__device__ __forceinline__ float bf2f(unsigned short u) {
    unsigned int v = (unsigned int)u << 16;
    float f; __builtin_memcpy(&f, &v, 4); return f;
}
__device__ __forceinline__ unsigned short f2bf(float f) {
    unsigned int v; __builtin_memcpy(&v, &f, 4);
    unsigned int lsb = (v >> 16) & 1u;
    v += 0x7fffu + lsb;               // round-to-nearest-even
    return (unsigned short)(v >> 16);
}

__device__ __forceinline__ void gl_lds16(const void* g, void* l) {
    __builtin_amdgcn_global_load_lds(
        (const __attribute__((address_space(1))) void*)g,
        (__attribute__((address_space(3))) void*)l, 16, 0, 0);
}

// ---------------------------------------------------------------------------
// K0: prep — W1 (512x256 bf16, rows 2n=Bre*g, 2n+1=Bim*g), W2 (256x512 bf16,
// cols 2n=Cre, 2n+1=-Cim), Lambda, Lambda^LC.  grid 256 x 256.
// ---------------------------------------------------------------------------
__global__ void prep_kernel(const float* __restrict__ nu_log,
                            const float* __restrict__ theta_log,
                            const float* __restrict__ B_re,
                            const float* __restrict__ B_im,
                            const float* __restrict__ C_re,
                            const float* __restrict__ C_im,
                            const float* __restrict__ gamma_log,
                            unsigned short* __restrict__ W1,
                            unsigned short* __restrict__ W2,
                            float2* __restrict__ Lambda,
                            float2* __restrict__ lamLc) {
    const int bid = blockIdx.x;   // n for W1, h for W2
    const int tid = threadIdx.x;  // h for W1, n for W2
    // W1
    {
        int n = bid, h = tid;
        float g = expf(gamma_log[n]);
        W1[(size_t)(2 * n + 0) * HDIM + h] = f2bf(B_re[(size_t)n * HDIM + h] * g);
        W1[(size_t)(2 * n + 1) * HDIM + h] = f2bf(B_im[(size_t)n * HDIM + h] * g);
    }
    // W2
    {
        int h = bid, n = tid;
        W2[(size_t)h * KDIM + 2 * n + 0] = f2bf(C_re[(size_t)h * NSTATE + n]);
        W2[(size_t)h * KDIM + 2 * n + 1] = f2bf(-C_im[(size_t)h * NSTATE + n]);
    }
    if (bid == 0) {
        int n = tid;
        float a = expf(nu_log[n]);
        float b = expf(theta_log[n]);
        float r = expf(-a);
        Lambda[n] = make_float2(r * cosf(b), r * sinf(b));
        float rl = expf(-a * (float)LC);
        float bl = b * (float)LC;
        lamLc[n] = make_float2(rl * cosf(bl), rl * sinf(bl));
    }
}

// ---------------------------------------------------------------------------
// K0b: cast x fp32 -> bf16 (8 elems/thread)
// ---------------------------------------------------------------------------
__launch_bounds__(256)
__global__ void castx_kernel(const float* __restrict__ x,
                             unsigned short* __restrict__ xb) {
    size_t i = ((size_t)blockIdx.x * 256 + threadIdx.x) * 8;
    float4 a = *(const float4*)(x + i);
    float4 b = *(const float4*)(x + i + 4);
    union { unsigned short s[8]; uint4 v; } u;
    u.s[0] = f2bf(a.x); u.s[1] = f2bf(a.y); u.s[2] = f2bf(a.z); u.s[3] = f2bf(a.w);
    u.s[4] = f2bf(b.x); u.s[5] = f2bf(b.y); u.s[6] = f2bf(b.z); u.s[7] = f2bf(b.w);
    *(uint4*)(xb + i) = u.v;
}

// ---------------------------------------------------------------------------
// MFMA bf16 GEMM, m97 structure: 128x128 tile, BK=32, 256 thr (4 waves),
// each wave 64x64 via 4x4 grid of 16x16x32 MFMAs. A: MxK, B: NxK (both
// k-contiguous). EPI2: out fp32 = acc + D[col]*x[idx]; else: out bf16.
// grid: (N/128, M/128), n-tiles fastest for A-tile L2 reuse.
// ---------------------------------------------------------------------------
template <int K, bool EPI2>
__launch_bounds__(256)
__global__ void gemm_mfma(const unsigned short* __restrict__ A,
                          const unsigned short* __restrict__ B,
                          int ldc,
                          unsigned short* __restrict__ Cb,
                          float* __restrict__ Cf,
                          const float* __restrict__ Dv,
                          const float* __restrict__ x) {
    __shared__ __align__(16) unsigned short As[128 * 32];
    __shared__ __align__(16) unsigned short Bs[128 * 32];

    const int tid  = threadIdx.x;
    const int wave = tid >> 6;
    const int lane = tid & 63;
    const int quad = lane >> 4;
    const int l16  = lane & 15;
    const int wm   = wave >> 1;   // 0..1
    const int wn   = wave & 1;    // 0..1
    const int m0   = blockIdx.y * 128;
    const int n0   = blockIdx.x * 128;
    const int srow = lane >> 2;          // 0..15 row within 16-row chunk
    const int scol = (lane & 3) * 8;     // bf16 elem offset within 32-elem row

    f32x4 acc[4][4] = {};

    for (int kt = 0; kt < K; kt += 32) {
        // stage A/B tiles: wave w handles row chunks 2w, 2w+1 (16 rows each).
        // LDS dest = uniform base + lane*16B, matching row-major [row][32] layout.
        #pragma unroll
        for (int q = 0; q < 2; ++q) {
            const int rr = (wave * 2 + q) * 16;
            const unsigned short* ga = A + (size_t)(m0 + rr + srow) * K + kt + scol;
            const unsigned short* gb = B + (size_t)(n0 + rr + srow) * K + kt + scol;
            gl_lds16(ga, As + rr * 32);
            gl_lds16(gb, Bs + rr * 32);
        }
        __syncthreads();   // drains vmcnt for global_load_lds

        bf16x8 af[4], bfr[4];
        #pragma unroll
        for (int i = 0; i < 4; ++i)
            af[i] = *(const bf16x8*)(As + ((size_t)(wm * 64 + i * 16 + l16)) * 32 + quad * 8);
        #pragma unroll
        for (int j = 0; j < 4; ++j)
            bfr[j] = *(const bf16x8*)(Bs + ((size_t)(wn * 64 + j * 16 + l16)) * 32 + quad * 8);
        #pragma unroll
        for (int i = 0; i < 4; ++i)
            #pragma unroll
            for (int j = 0; j < 4; ++j)
                acc[i][j] = __builtin_amdgcn_mfma_f32_16x16x32_bf16(af[i], bfr[j], acc[i][j], 0, 0, 0);
        __syncthreads();   // protect LDS for next overwrite
    }

    // epilogue: C/D layout col=lane&15, row=quad*4+reg
    #pragma unroll
    for (int i = 0; i < 4; ++i) {
        const int rowb = m0 + wm * 64 + i * 16 + quad * 4;
        #pragma unroll
        for (int j = 0; j < 4; ++j) {
            const int col = n0 + wn * 64 + j * 16 + l16;
            #pragma unroll
            for (int r = 0; r < 4; ++r) {
                const size_t idx = (size_t)(rowb + r) * ldc + col;
                if (EPI2) {
                    Cf[idx] = fmaf(Dv[col], x[idx], acc[i][j][r]);
                } else {
                    Cb[idx] = f2bf(acc[i][j][r]);
                }
            }
        }
    }
}

// ---------------------------------------------------------------------------
// K2: per-chunk local scan over bf16 Bu (interleaved re/im), carry in fp32
// ---------------------------------------------------------------------------
__launch_bounds__(256)
__global__ void scan1_kernel(const unsigned short* __restrict__ Bu,
                             const float2* __restrict__ Lambda,
                             float2* __restrict__ chunk_local) {
    const int c = blockIdx.x;
    const int n = threadIdx.x;
    const float2 lam = Lambda[n];
    float zr = 0.f, zi = 0.f;
    const unsigned short* p = Bu + (size_t)c * LC * KDIM + 2 * n;
    #pragma unroll 8
    for (int l = 0; l < LC; ++l) {
        unsigned int v = *(const unsigned int*)(p + (size_t)l * KDIM);
        float br = bf2f((unsigned short)(v & 0xffffu));
        float bi = bf2f((unsigned short)(v >> 16));
        float nzr = fmaf(lam.x, zr, fmaf(-lam.y, zi, br));
        float nzi = fmaf(lam.x, zi, fmaf(lam.y, zr, bi));
        zr = nzr; zi = nzi;
    }
    chunk_local[c * NSTATE + n] = make_float2(zr, zi);
}

// ---------------------------------------------------------------------------
// K3: sequential scan over chunk carries (1 block)
// ---------------------------------------------------------------------------
__launch_bounds__(256)
__global__ void scan2_kernel(const float2* __restrict__ chunk_local,
                             const float2* __restrict__ lamLc,
                             float2* __restrict__ chunk_prefix) {
    const int n = threadIdx.x;
    const float2 lam = lamLc[n];
    float zr = 0.f, zi = 0.f;
    #pragma unroll 4
    for (int c = 0; c < NCHUNK; ++c) {
        float2 b = chunk_local[c * NSTATE + n];
        float nzr = fmaf(lam.x, zr, fmaf(-lam.y, zi, b.x));
        float nzi = fmaf(lam.x, zi, fmaf(lam.y, zr, b.y));
        zr = nzr; zi = nzi;
        chunk_prefix[c * NSTATE + n] = make_float2(zr, zi);
    }
}

// ---------------------------------------------------------------------------
// K4: re-scan with true carry-in, write bf16 states in place over Bu
// ---------------------------------------------------------------------------
__launch_bounds__(256)
__global__ void scan3_kernel(unsigned short* __restrict__ Bu,
                             const float2* __restrict__ Lambda,
                             const float2* __restrict__ chunk_prefix) {
    const int c = blockIdx.x;
    const int n = threadIdx.x;
    const float2 lam = Lambda[n];
    float zr = 0.f, zi = 0.f;
    if (c > 0) {
        float2 z0 = chunk_prefix[(c - 1) * NSTATE + n];
        zr = z0.x; zi = z0.y;
    }
    unsigned short* p = Bu + (size_t)c * LC * KDIM + 2 * n;
    #pragma unroll 8
    for (int l = 0; l < LC; ++l) {
        unsigned int v = *(const unsigned int*)(p + (size_t)l * KDIM);
        float br = bf2f((unsigned short)(v & 0xffffu));
        float bi = bf2f((unsigned short)(v >> 16));
        float nzr = fmaf(lam.x, zr, fmaf(-lam.y, zi, br));
        float nzi = fmaf(lam.x, zi, fmaf(lam.y, zr, bi));
        zr = nzr; zi = nzi;
        unsigned int o = (unsigned int)f2bf(nzr) | ((unsigned int)f2bf(nzi) << 16);
        *(unsigned int*)(p + (size_t)l * KDIM) = o;
    }
}

// ---------------------------------------------------------------------------
// Host launch
// ---------------------------------------------------------------------------
extern "C" void kernel_launch(void* const* d_in, const int* in_sizes, int n_in,
                              void* d_out, int out_size, void* d_ws, size_t ws_size,
                              hipStream_t stream) {
    const float* x         = (const float*)d_in[0];
    const float* nu_log    = (const float*)d_in[1];
    const float* theta_log = (const float*)d_in[2];
    const float* B_re      = (const float*)d_in[3];
    const float* B_im      = (const float*)d_in[4];
    const float* C_re      = (const float*)d_in[5];
    const float* C_im      = (const float*)d_in[6];
    const float* Dvec      = (const float*)d_in[7];
    const float* gamma_log = (const float*)d_in[8];
    float* out = (float*)d_out;

    char* ws = (char*)d_ws;
    const size_t BU_BYTES    = (size_t)L_SEQ * KDIM * 2;          // 134 MB bf16
    const size_t XB_BYTES    = (size_t)L_SEQ * HDIM * 2;          // 67 MB bf16
    const size_t W1_BYTES    = (size_t)KDIM * HDIM * 2;           // 256 KB
    const size_t W2_BYTES    = (size_t)HDIM * KDIM * 2;           // 256 KB
    const size_t LAM_BYTES   = (size_t)NSTATE * sizeof(float2);
    const size_t CHUNK_BYTES = (size_t)NCHUNK * NSTATE * sizeof(float2);  // 2 MB

    size_t off = 0;
    unsigned short* Bu  = (unsigned short*)(ws + off); off += BU_BYTES;
    unsigned short* xb  = (unsigned short*)(ws + off); off += XB_BYTES;
    unsigned short* W1  = (unsigned short*)(ws + off); off += W1_BYTES;
    unsigned short* W2  = (unsigned short*)(ws + off); off += W2_BYTES;
    float2* Lambda      = (float2*)(ws + off); off += LAM_BYTES;
    float2* lamLc       = (float2*)(ws + off); off += LAM_BYTES;
    float2* chunk_local = (float2*)(ws + off); off += CHUNK_BYTES;
    float2* chunk_pref  = (float2*)(ws + off); off += CHUNK_BYTES;
    if (ws_size < off) return;

    prep_kernel<<<dim3(256), dim3(256), 0, stream>>>(
        nu_log, theta_log, B_re, B_im, C_re, C_im, gamma_log, W1, W2, Lambda, lamLc);

    castx_kernel<<<dim3((L_SEQ * HDIM) / (256 * 8)), dim3(256), 0, stream>>>(x, xb);

    // GEMM1: (L x 256) * (512 x 256)^T -> Bu (L x 512 bf16, interleaved re/im)
    gemm_mfma<HDIM, false><<<dim3(KDIM / 128, L_SEQ / 128), dim3(256), 0, stream>>>(
        xb, W1, KDIM, Bu, nullptr, nullptr, nullptr);

    scan1_kernel<<<dim3(NCHUNK), dim3(NSTATE), 0, stream>>>(Bu, Lambda, chunk_local);
    scan2_kernel<<<dim3(1), dim3(NSTATE), 0, stream>>>(chunk_local, lamLc, chunk_pref);
    scan3_kernel<<<dim3(NCHUNK), dim3(NSTATE), 0, stream>>>(Bu, Lambda, chunk_pref);

    // GEMM2: (L x 512) * (256 x 512)^T + D*x -> out (L x 256 fp32)
    gemm_mfma<KDIM, true><<<dim3(HDIM / 128, L_SEQ / 128), dim3(256), 0, stream>>>(
        Bu, W2, HDIM, nullptr, out, Dvec, x);
}

// Round 3
// 468.741 us; speedup vs baseline: 3.4885x; 1.2543x over previous
//
#include <hip/hip_runtime.h>
#include <math.h>

// Problem constants
#define L_SEQ 131072
#define NSTATE 256
#define HDIM   256
#define KDIM   512            // 2*NSTATE: re/im interleaved columns
#define LC     128            // scan chunk length
#define NCHUNK (L_SEQ / LC)   // 1024

typedef __bf16 bf16x8 __attribute__((ext_vector_type(8)));
typedef float  f32x4  __attribute__((ext_vector_type(4)));

__device__ __forceinline__ float bf2f(unsigned short u) {
    unsigned int v = (unsigned int)u << 16;
    float f; __builtin_memcpy(&f, &v, 4); return f;
}
__device__ __forceinline__ unsigned short f2bf(float f) {
    unsigned int v; __builtin_memcpy(&v, &f, 4);
    unsigned int lsb = (v >> 16) & 1u;
    v += 0x7fffu + lsb;               // round-to-nearest-even
    return (unsigned short)(v >> 16);
}

__device__ __forceinline__ void gl_lds16(const void* g, void* l) {
    __builtin_amdgcn_global_load_lds(
        (const __attribute__((address_space(1))) void*)g,
        (__attribute__((address_space(3))) void*)l, 16, 0, 0);
}

// ---------------------------------------------------------------------------
// K0: prep — W1 (512x256 bf16, rows 2n=Bre*g, 2n+1=Bim*g), W2 (256x512 bf16,
// cols 2n=Cre, 2n+1=-Cim), Lambda, Lambda^LC.  grid 256 x 256.
// ---------------------------------------------------------------------------
__global__ void prep_kernel(const float* __restrict__ nu_log,
                            const float* __restrict__ theta_log,
                            const float* __restrict__ B_re,
                            const float* __restrict__ B_im,
                            const float* __restrict__ C_re,
                            const float* __restrict__ C_im,
                            const float* __restrict__ gamma_log,
                            unsigned short* __restrict__ W1,
                            unsigned short* __restrict__ W2,
                            float2* __restrict__ Lambda,
                            float2* __restrict__ lamLc) {
    const int bid = blockIdx.x;   // n for W1, h for W2
    const int tid = threadIdx.x;  // h for W1, n for W2
    // W1
    {
        int n = bid, h = tid;
        float g = expf(gamma_log[n]);
        W1[(size_t)(2 * n + 0) * HDIM + h] = f2bf(B_re[(size_t)n * HDIM + h] * g);
        W1[(size_t)(2 * n + 1) * HDIM + h] = f2bf(B_im[(size_t)n * HDIM + h] * g);
    }
    // W2
    {
        int h = bid, n = tid;
        W2[(size_t)h * KDIM + 2 * n + 0] = f2bf(C_re[(size_t)h * NSTATE + n]);
        W2[(size_t)h * KDIM + 2 * n + 1] = f2bf(-C_im[(size_t)h * NSTATE + n]);
    }
    if (bid == 0) {
        int n = tid;
        float a = expf(nu_log[n]);
        float b = expf(theta_log[n]);
        float r = expf(-a);
        Lambda[n] = make_float2(r * cosf(b), r * sinf(b));
        float rl = expf(-a * (float)LC);
        float bl = b * (float)LC;
        lamLc[n] = make_float2(rl * cosf(bl), rl * sinf(bl));
    }
}

// ---------------------------------------------------------------------------
// K0b: cast x fp32 -> bf16 (8 elems/thread)
// ---------------------------------------------------------------------------
__launch_bounds__(256)
__global__ void castx_kernel(const float* __restrict__ x,
                             unsigned short* __restrict__ xb) {
    size_t i = ((size_t)blockIdx.x * 256 + threadIdx.x) * 8;
    float4 a = *(const float4*)(x + i);
    float4 b = *(const float4*)(x + i + 4);
    union { unsigned short s[8]; uint4 v; } u;
    u.s[0] = f2bf(a.x); u.s[1] = f2bf(a.y); u.s[2] = f2bf(a.z); u.s[3] = f2bf(a.w);
    u.s[4] = f2bf(b.x); u.s[5] = f2bf(b.y); u.s[6] = f2bf(b.z); u.s[7] = f2bf(b.w);
    *(uint4*)(xb + i) = u.v;
}

// ---------------------------------------------------------------------------
// MFMA bf16 GEMM, m97 structure: 128x128 tile, BK=32, 256 thr (4 waves),
// each wave 64x64 via 4x4 grid of 16x16x32 MFMAs. A: MxK, B: NxK (both
// k-contiguous). EPI2: out fp32 = acc + D[col]*x[idx]; else: out bf16.
// grid: (N/128, M/128), n-tiles fastest for A-tile L2 reuse.
// ---------------------------------------------------------------------------
template <int K, bool EPI2>
__launch_bounds__(256)
__global__ void gemm_mfma(const unsigned short* __restrict__ A,
                          const unsigned short* __restrict__ B,
                          int ldc,
                          unsigned short* __restrict__ Cb,
                          float* __restrict__ Cf,
                          const float* __restrict__ Dv,
                          const float* __restrict__ x) {
    __shared__ __align__(16) unsigned short As[128 * 32];
    __shared__ __align__(16) unsigned short Bs[128 * 32];

    const int tid  = threadIdx.x;
    const int wave = tid >> 6;
    const int lane = tid & 63;
    const int quad = lane >> 4;
    const int l16  = lane & 15;
    const int wm   = wave >> 1;   // 0..1
    const int wn   = wave & 1;    // 0..1
    const int m0   = blockIdx.y * 128;
    const int n0   = blockIdx.x * 128;
    const int srow = lane >> 2;          // 0..15 row within 16-row chunk
    const int scol = (lane & 3) * 8;     // bf16 elem offset within 32-elem row

    f32x4 acc[4][4] = {};

    for (int kt = 0; kt < K; kt += 32) {
        #pragma unroll
        for (int q = 0; q < 2; ++q) {
            const int rr = (wave * 2 + q) * 16;
            const unsigned short* ga = A + (size_t)(m0 + rr + srow) * K + kt + scol;
            const unsigned short* gb = B + (size_t)(n0 + rr + srow) * K + kt + scol;
            gl_lds16(ga, As + rr * 32);
            gl_lds16(gb, Bs + rr * 32);
        }
        __syncthreads();

        bf16x8 af[4], bfr[4];
        #pragma unroll
        for (int i = 0; i < 4; ++i)
            af[i] = *(const bf16x8*)(As + ((size_t)(wm * 64 + i * 16 + l16)) * 32 + quad * 8);
        #pragma unroll
        for (int j = 0; j < 4; ++j)
            bfr[j] = *(const bf16x8*)(Bs + ((size_t)(wn * 64 + j * 16 + l16)) * 32 + quad * 8);
        #pragma unroll
        for (int i = 0; i < 4; ++i)
            #pragma unroll
            for (int j = 0; j < 4; ++j)
                acc[i][j] = __builtin_amdgcn_mfma_f32_16x16x32_bf16(af[i], bfr[j], acc[i][j], 0, 0, 0);
        __syncthreads();
    }

    // epilogue: C/D layout col=lane&15, row=quad*4+reg
    #pragma unroll
    for (int i = 0; i < 4; ++i) {
        const int rowb = m0 + wm * 64 + i * 16 + quad * 4;
        #pragma unroll
        for (int j = 0; j < 4; ++j) {
            const int col = n0 + wn * 64 + j * 16 + l16;
            #pragma unroll
            for (int r = 0; r < 4; ++r) {
                const size_t idx = (size_t)(rowb + r) * ldc + col;
                if (EPI2) {
                    Cf[idx] = fmaf(Dv[col], x[idx], acc[i][j][r]);
                } else {
                    Cb[idx] = f2bf(acc[i][j][r]);
                }
            }
        }
    }
}

// ---------------------------------------------------------------------------
// K2: per-chunk local scan over bf16 Bu (interleaved re/im), carry in fp32
// ---------------------------------------------------------------------------
__launch_bounds__(256)
__global__ void scan1_kernel(const unsigned short* __restrict__ Bu,
                             const float2* __restrict__ Lambda,
                             float2* __restrict__ chunk_local) {
    const int c = blockIdx.x;
    const int n = threadIdx.x;
    const float2 lam = Lambda[n];
    float zr = 0.f, zi = 0.f;
    const unsigned short* p = Bu + (size_t)c * LC * KDIM + 2 * n;
    #pragma unroll 8
    for (int l = 0; l < LC; ++l) {
        unsigned int v = *(const unsigned int*)(p + (size_t)l * KDIM);
        float br = bf2f((unsigned short)(v & 0xffffu));
        float bi = bf2f((unsigned short)(v >> 16));
        float nzr = fmaf(lam.x, zr, fmaf(-lam.y, zi, br));
        float nzi = fmaf(lam.x, zi, fmaf(lam.y, zr, bi));
        zr = nzr; zi = nzi;
    }
    chunk_local[c * NSTATE + n] = make_float2(zr, zi);
}

// ---------------------------------------------------------------------------
// K3: Kogge-Stone parallel scan over the 1024 chunk carries.
// grid: NSTATE blocks (one per channel n) x NCHUNK threads (one per chunk c).
// Coefficient is constant (lamLc) so step-k coefficient = lamLc^(2^k),
// computed by repeated squaring (wave-uniform scalar math).
// chunk_prefix[c][n] = exact state at END of chunk c.
// ---------------------------------------------------------------------------
__launch_bounds__(1024)
__global__ void scan2_kernel(const float2* __restrict__ chunk_local,
                             const float2* __restrict__ lamLc,
                             float2* __restrict__ chunk_prefix) {
    __shared__ float2 sbuf[NCHUNK];
    const int n = blockIdx.x;
    const int c = threadIdx.x;
    float2 lam = lamLc[n];          // coefficient for step 1
    float2 b = chunk_local[c * NSTATE + n];
    sbuf[c] = b;
    __syncthreads();
    #pragma unroll
    for (int step = 1; step < NCHUNK; step <<= 1) {
        float2 prev = make_float2(0.f, 0.f);
        if (c >= step) prev = sbuf[c - step];
        __syncthreads();
        if (c >= step) {
            // b += lam * prev (complex)
            b.x = fmaf(lam.x, prev.x, fmaf(-lam.y, prev.y, b.x));
            b.y = fmaf(lam.x, prev.y, fmaf(lam.y, prev.x, b.y));
        }
        sbuf[c] = b;
        // lam = lam^2
        float lr = fmaf(lam.x, lam.x, -lam.y * lam.y);
        float li = 2.f * lam.x * lam.y;
        lam = make_float2(lr, li);
        __syncthreads();
    }
    chunk_prefix[c * NSTATE + n] = b;
}

// ---------------------------------------------------------------------------
// K4: re-scan with true carry-in, write bf16 states in place over Bu
// ---------------------------------------------------------------------------
__launch_bounds__(256)
__global__ void scan3_kernel(unsigned short* __restrict__ Bu,
                             const float2* __restrict__ Lambda,
                             const float2* __restrict__ chunk_prefix) {
    const int c = blockIdx.x;
    const int n = threadIdx.x;
    const float2 lam = Lambda[n];
    float zr = 0.f, zi = 0.f;
    if (c > 0) {
        float2 z0 = chunk_prefix[(c - 1) * NSTATE + n];
        zr = z0.x; zi = z0.y;
    }
    unsigned short* p = Bu + (size_t)c * LC * KDIM + 2 * n;
    #pragma unroll 8
    for (int l = 0; l < LC; ++l) {
        unsigned int v = *(const unsigned int*)(p + (size_t)l * KDIM);
        float br = bf2f((unsigned short)(v & 0xffffu));
        float bi = bf2f((unsigned short)(v >> 16));
        float nzr = fmaf(lam.x, zr, fmaf(-lam.y, zi, br));
        float nzi = fmaf(lam.x, zi, fmaf(lam.y, zr, bi));
        zr = nzr; zi = nzi;
        unsigned int o = (unsigned int)f2bf(nzr) | ((unsigned int)f2bf(nzi) << 16);
        *(unsigned int*)(p + (size_t)l * KDIM) = o;
    }
}

// ---------------------------------------------------------------------------
// Host launch
// ---------------------------------------------------------------------------
extern "C" void kernel_launch(void* const* d_in, const int* in_sizes, int n_in,
                              void* d_out, int out_size, void* d_ws, size_t ws_size,
                              hipStream_t stream) {
    const float* x         = (const float*)d_in[0];
    const float* nu_log    = (const float*)d_in[1];
    const float* theta_log = (const float*)d_in[2];
    const float* B_re      = (const float*)d_in[3];
    const float* B_im      = (const float*)d_in[4];
    const float* C_re      = (const float*)d_in[5];
    const float* C_im      = (const float*)d_in[6];
    const float* Dvec      = (const float*)d_in[7];
    const float* gamma_log = (const float*)d_in[8];
    float* out = (float*)d_out;

    char* ws = (char*)d_ws;
    const size_t BU_BYTES    = (size_t)L_SEQ * KDIM * 2;          // 134 MB bf16
    const size_t XB_BYTES    = (size_t)L_SEQ * HDIM * 2;          // 67 MB bf16
    const size_t W1_BYTES    = (size_t)KDIM * HDIM * 2;           // 256 KB
    const size_t W2_BYTES    = (size_t)HDIM * KDIM * 2;           // 256 KB
    const size_t LAM_BYTES   = (size_t)NSTATE * sizeof(float2);
    const size_t CHUNK_BYTES = (size_t)NCHUNK * NSTATE * sizeof(float2);  // 2 MB

    size_t off = 0;
    unsigned short* Bu  = (unsigned short*)(ws + off); off += BU_BYTES;
    unsigned short* xb  = (unsigned short*)(ws + off); off += XB_BYTES;
    unsigned short* W1  = (unsigned short*)(ws + off); off += W1_BYTES;
    unsigned short* W2  = (unsigned short*)(ws + off); off += W2_BYTES;
    float2* Lambda      = (float2*)(ws + off); off += LAM_BYTES;
    float2* lamLc       = (float2*)(ws + off); off += LAM_BYTES;
    float2* chunk_local = (float2*)(ws + off); off += CHUNK_BYTES;
    float2* chunk_pref  = (float2*)(ws + off); off += CHUNK_BYTES;
    if (ws_size < off) return;

    prep_kernel<<<dim3(256), dim3(256), 0, stream>>>(
        nu_log, theta_log, B_re, B_im, C_re, C_im, gamma_log, W1, W2, Lambda, lamLc);

    castx_kernel<<<dim3((L_SEQ * HDIM) / (256 * 8)), dim3(256), 0, stream>>>(x, xb);

    // GEMM1: (L x 256) * (512 x 256)^T -> Bu (L x 512 bf16, interleaved re/im)
    gemm_mfma<HDIM, false><<<dim3(KDIM / 128, L_SEQ / 128), dim3(256), 0, stream>>>(
        xb, W1, KDIM, Bu, nullptr, nullptr, nullptr);

    scan1_kernel<<<dim3(NCHUNK), dim3(NSTATE), 0, stream>>>(Bu, Lambda, chunk_local);
    scan2_kernel<<<dim3(NSTATE), dim3(NCHUNK), 0, stream>>>(chunk_local, lamLc, chunk_pref);
    scan3_kernel<<<dim3(NCHUNK), dim3(NSTATE), 0, stream>>>(Bu, Lambda, chunk_pref);

    // GEMM2: (L x 512) * (256 x 512)^T + D*x -> out (L x 256 fp32)
    gemm_mfma<KDIM, true><<<dim3(HDIM / 128, L_SEQ / 128), dim3(256), 0, stream>>>(
        Bu, W2, HDIM, nullptr, out, Dvec, x);
}